// Round 7
// baseline (451.144 us; speedup 1.0000x reference)
//
#include <hip/hip_runtime.h>

#define NN     4096
#define MAXD   32      // degree cap (WS k=4 max degree ~12)
#define WUNR   8       // fully-unrolled ELL width; rows with c>8 take tail loop
#define TB     4       // tokens per round
#define ROUNDS 8       // rounds per block -> 32 tokens/block
#define BLK    512
#define QN     (NN / BLK)   // 8 output rows per thread

// Phase 1: build padded ELL (column-major [j][o]) of W*M, deterministically.
// One wave per row; float4 mask reads + 4 ballots; prefix popcount keeps
// indices sorted ascending -> fixed fp32 summation order. Weight read only at
// nz positions (sparse). float2 {idx bitcast, w}; padding {0, 0.0f}.
__global__ __launch_bounds__(64) void build_ell_kernel(
    const float* __restrict__ weight, const float* __restrict__ mask,
    float2* __restrict__ ell, int* __restrict__ cnt) {
  const int o = blockIdx.x;
  const int lane = threadIdx.x;
  if (lane < MAXD) {
    float2 z; z.x = __uint_as_float(0u); z.y = 0.0f;
    ell[(size_t)lane * NN + o] = z;
  }
  __syncthreads();   // one wave: orders padding stores before entry stores
  const float* mrow = mask + (size_t)o * NN;
  const float* wrow = weight + (size_t)o * NN;
  const unsigned long long lt = (lane == 63) ? 0x7fffffffffffffffull
                                             : ((1ull << lane) - 1ull);
  int count = 0;
  for (int base = 0; base < NN; base += 256) {
    const int c0 = base + 4 * lane;
    const float4 mv = *(const float4*)(mrow + c0);
    const bool b0 = mv.x != 0.f, b1 = mv.y != 0.f, b2 = mv.z != 0.f, b3 = mv.w != 0.f;
    const unsigned long long a0 = __ballot(b0), a1 = __ballot(b1),
                             a2 = __ballot(b2), a3 = __ballot(b3);
    int pos = count + __popcll(a0 & lt) + __popcll(a1 & lt)
                    + __popcll(a2 & lt) + __popcll(a3 & lt);
    if (b0) { if (pos < MAXD) { float2 e; e.x = __uint_as_float(c0 + 0); e.y = wrow[c0 + 0]; ell[(size_t)pos * NN + o] = e; } ++pos; }
    if (b1) { if (pos < MAXD) { float2 e; e.x = __uint_as_float(c0 + 1); e.y = wrow[c0 + 1]; ell[(size_t)pos * NN + o] = e; } ++pos; }
    if (b2) { if (pos < MAXD) { float2 e; e.x = __uint_as_float(c0 + 2); e.y = wrow[c0 + 2]; ell[(size_t)pos * NN + o] = e; } ++pos; }
    if (b3) { if (pos < MAXD) { float2 e; e.x = __uint_as_float(c0 + 3); e.y = wrow[c0 + 3]; ell[(size_t)pos * NN + o] = e; } ++pos; }
    count += __popcll(a0) + __popcll(a1) + __popcll(a2) + __popcll(a3);
  }
  if (lane == 0) cnt[o] = (count < MAXD) ? count : MAXD;
}

// Phase 2: persistent SpMM, 512 blocks (2/CU), single 64 KiB LDS buffer,
// prefetch-to-regs + raw barriers (no vmcnt drain in the loop: out-stores and
// next-round x loads stay in flight across barriers).
__global__ __launch_bounds__(BLK, 4) void ws_spmm_kernel(   // VGPR cap 128
    const float* __restrict__ x, const float* __restrict__ bias,
    const float2* __restrict__ ell, const int* __restrict__ cnt,
    float* __restrict__ out) {
  __shared__ float4 xs[NN];                          // [col] -> 4 tokens, 64 KiB
  const int tid = threadIdx.x;
  const size_t tok0 = (size_t)blockIdx.x * (TB * ROUNDS);

  // Hoist cnt + bias (16 regs, reused all rounds).
  int   cn[QN];
  float bs[QN];
#pragma unroll
  for (int q = 0; q < QN; ++q) {
    cn[q] = cnt[q * BLK + tid];
    bs[q] = bias[q * BLK + tid];
  }

  // Stage round 0.
  {
    const float* __restrict__ xb = x + tok0 * NN;
#pragma unroll
    for (int i = 0; i < QN; ++i) {
      const int c2 = tid + i * BLK;
      xs[c2] = make_float4(xb[c2], xb[NN + c2], xb[2 * NN + c2], xb[3 * NN + c2]);
    }
  }
  asm volatile("s_waitcnt lgkmcnt(0)" ::: "memory");
  __builtin_amdgcn_s_barrier();

  for (int it = 0; it < ROUNDS; ++it) {
    // Issue next round's x loads early (latency hides under compute).
    float xr[TB][QN];
    if (it + 1 < ROUNDS) {
      const float* __restrict__ xb = x + (tok0 + (size_t)(it + 1) * TB) * NN;
#pragma unroll
      for (int i = 0; i < QN; ++i) {
        const int c2 = tid + i * BLK;
#pragma unroll
        for (int t = 0; t < TB; ++t)
          xr[t][i] = xb[t * NN + c2];
      }
    }

    // Compute current round: QN output rows x 4 tokens per thread.
    const size_t t0 = tok0 + (size_t)it * TB;
#pragma unroll
    for (int q = 0; q < QN; ++q) {
      const int o = q * BLK + tid;
      float2 e[WUNR];
#pragma unroll
      for (int j = 0; j < WUNR; ++j)
        e[j] = ell[(size_t)j * NN + o];              // coalesced dwordx2, L2-hit
      float a0 = 0.f, a1 = 0.f, a2 = 0.f, a3 = 0.f;
#pragma unroll
      for (int j = 0; j < WUNR; ++j) {
        const unsigned ix = __float_as_uint(e[j].x);
        const float w = e[j].y;
        const float4 xv = xs[ix];                    // ds_read_b128: 4 tokens
        a0 = fmaf(xv.x, w, a0);
        a1 = fmaf(xv.y, w, a1);
        a2 = fmaf(xv.z, w, a2);
        a3 = fmaf(xv.w, w, a3);
      }
      for (int j = WUNR; j < cn[q]; ++j) {           // rare tail (degree > 8)
        const float2 et = ell[(size_t)j * NN + o];
        const unsigned ix = __float_as_uint(et.x);
        const float w = et.y;
        const float4 xv = xs[ix];
        a0 = fmaf(xv.x, w, a0);
        a1 = fmaf(xv.y, w, a1);
        a2 = fmaf(xv.z, w, a2);
        a3 = fmaf(xv.w, w, a3);
      }
      float* op = out + t0 * NN + o;
      op[0]      = a0 + bs[q];
      op[NN]     = a1 + bs[q];
      op[2 * NN] = a2 + bs[q];
      op[3 * NN] = a3 + bs[q];
    }

    // Barrier 1: all waves done reading xs (own ds_reads drained by FMA deps +
    // lgkmcnt(0)); no vmcnt drain -> stores/prefetch stay outstanding.
    asm volatile("s_waitcnt lgkmcnt(0)" ::: "memory");
    __builtin_amdgcn_s_barrier();

    // Overwrite xs with prefetched regs (compiler waits vmcnt only for xr).
    if (it + 1 < ROUNDS) {
#pragma unroll
      for (int i = 0; i < QN; ++i) {
        const int c2 = tid + i * BLK;
        xs[c2] = make_float4(xr[0][i], xr[1][i], xr[2][i], xr[3][i]);
      }
    }
    // Barrier 2: new tile visible.
    asm volatile("s_waitcnt lgkmcnt(0)" ::: "memory");
    __builtin_amdgcn_s_barrier();
  }
}

extern "C" void kernel_launch(void* const* d_in, const int* in_sizes, int n_in,
                              void* d_out, int out_size, void* d_ws, size_t ws_size,
                              hipStream_t stream) {
  const float* x      = (const float*)d_in[0];
  const float* weight = (const float*)d_in[1];
  const float* bias   = (const float*)d_in[2];
  const float* mask   = (const float*)d_in[3];
  float* out = (float*)d_out;

  char* ws = (char*)d_ws;
  float2* ell = (float2*)ws;                                     // 1 MiB
  int*    cnt = (int*)(ws + (size_t)MAXD * NN * sizeof(float2)); // 16 KiB

  const int tokens = in_sizes[0] / NN;               // 16384
  const int nblk = tokens / (TB * ROUNDS);           // 512 -> 2 blocks/CU

  build_ell_kernel<<<NN, 64, 0, stream>>>(weight, mask, ell, cnt);
  ws_spmm_kernel<<<nblk, BLK, 0, stream>>>(x, bias, ell, cnt, out);
}

// Round 8
// 333.289 us; speedup vs baseline: 1.3536x; 1.3536x over previous
//
#include <hip/hip_runtime.h>

#define NN     4096
#define MAXD   32      // degree cap (WS k=4 max degree ~12)
#define WUNR   8       // fully-unrolled ELL width; rows with c>8 take tail loop
#define TB     4       // tokens per round
#define ROUNDS 16      // rounds per block -> 64 tokens/block
#define BLK    640     // 8 consumer waves (512) + 2 producer waves (128)
#define CONS   512
#define QN     (NN / CONS)  // 8 output rows per consumer thread

// Phase 1: build padded ELL (column-major [j][o]) of W*M, deterministically.
// One wave per row; float4 mask reads + 4 ballots; prefix popcount keeps
// indices sorted ascending -> fixed fp32 summation order.
__global__ __launch_bounds__(64) void build_ell_kernel(
    const float* __restrict__ weight, const float* __restrict__ mask,
    float2* __restrict__ ell, int* __restrict__ cnt) {
  const int o = blockIdx.x;
  const int lane = threadIdx.x;
  if (lane < MAXD) {
    float2 z; z.x = __uint_as_float(0u); z.y = 0.0f;
    ell[(size_t)lane * NN + o] = z;
  }
  __syncthreads();
  const float* mrow = mask + (size_t)o * NN;
  const float* wrow = weight + (size_t)o * NN;
  const unsigned long long lt = (lane == 63) ? 0x7fffffffffffffffull
                                             : ((1ull << lane) - 1ull);
  int count = 0;
  for (int base = 0; base < NN; base += 256) {
    const int c0 = base + 4 * lane;
    const float4 mv = *(const float4*)(mrow + c0);
    const bool b0 = mv.x != 0.f, b1 = mv.y != 0.f, b2 = mv.z != 0.f, b3 = mv.w != 0.f;
    const unsigned long long a0 = __ballot(b0), a1 = __ballot(b1),
                             a2 = __ballot(b2), a3 = __ballot(b3);
    int pos = count + __popcll(a0 & lt) + __popcll(a1 & lt)
                    + __popcll(a2 & lt) + __popcll(a3 & lt);
    if (b0) { if (pos < MAXD) { float2 e; e.x = __uint_as_float(c0 + 0); e.y = wrow[c0 + 0]; ell[(size_t)pos * NN + o] = e; } ++pos; }
    if (b1) { if (pos < MAXD) { float2 e; e.x = __uint_as_float(c0 + 1); e.y = wrow[c0 + 1]; ell[(size_t)pos * NN + o] = e; } ++pos; }
    if (b2) { if (pos < MAXD) { float2 e; e.x = __uint_as_float(c0 + 2); e.y = wrow[c0 + 2]; ell[(size_t)pos * NN + o] = e; } ++pos; }
    if (b3) { if (pos < MAXD) { float2 e; e.x = __uint_as_float(c0 + 3); e.y = wrow[c0 + 3]; ell[(size_t)pos * NN + o] = e; } ++pos; }
    count += __popcll(a0) + __popcll(a1) + __popcll(a2) + __popcll(a3);
  }
  if (lane == 0) cnt[o] = (count < MAXD) ? count : MAXD;
}

// Phase 2: producer/consumer persistent SpMM. 1 block/CU (grid 256).
// Waves 8-9 (tid>=512): stage next token tile into the other LDS buffer
//   (coalesced scalar loads, conflict-free ds_write_b128; compiler emits
//   counted vmcnt for load->write deps — no vmcnt(0) anywhere in the loop).
// Waves 0-7 (tid<512): gather-compute current tile (ds_read_b128 = 4 tokens
//   per ELL index), out-stores left in flight across barriers.
// Round sync: lgkmcnt(0) + raw s_barrier (lgkmcnt(0) guarantees consumer
//   ds_reads of buf are complete before producers overwrite buf next round).
__global__ __launch_bounds__(BLK) void ws_spmm_kernel(
    const float* __restrict__ x, const float* __restrict__ bias,
    const float2* __restrict__ ell, const int* __restrict__ cnt,
    float* __restrict__ out) {
  __shared__ float4 xs[2][NN];                       // 2 x 64 KiB = 128 KiB
  const int tid = threadIdx.x;
  const size_t tok0 = (size_t)blockIdx.x * (TB * ROUNDS);

  int   cn[QN];
  float bs[QN];
  if (tid < CONS) {                                  // consumers: hoist cnt/bias
#pragma unroll
    for (int q = 0; q < QN; ++q) {
      cn[q] = cnt[q * CONS + tid];
      bs[q] = bias[q * CONS + tid];
    }
  } else {                                           // producers: stage tile 0
    const int pw = (tid - CONS) >> 6;                // 0 or 1
    const int pl = tid & 63;
    const float* __restrict__ xb = x + tok0 * NN;
#pragma unroll 8
    for (int i = 0; i < 32; ++i) {
      const int c = pw * 2048 + pl + (i << 6);       // coalesced per token row
      xs[0][c] = make_float4(xb[c], xb[NN + c], xb[2 * NN + c], xb[3 * NN + c]);
    }
  }
  asm volatile("s_waitcnt lgkmcnt(0)" ::: "memory");
  __builtin_amdgcn_s_barrier();

  for (int it = 0; it < ROUNDS; ++it) {
    if (tid >= CONS) {
      // ---- producers: stage tile it+1 into buf^1 ----
      if (it + 1 < ROUNDS) {
        const int pw = (tid - CONS) >> 6;
        const int pl = tid & 63;
        const float* __restrict__ xb = x + (tok0 + (size_t)(it + 1) * TB) * NN;
        float4* __restrict__ dst = xs[(it + 1) & 1];
#pragma unroll 8
        for (int i = 0; i < 32; ++i) {
          const int c = pw * 2048 + pl + (i << 6);
          dst[c] = make_float4(xb[c], xb[NN + c], xb[2 * NN + c], xb[3 * NN + c]);
        }
      }
    } else {
      // ---- consumers: compute tile it ----
      const float4* __restrict__ xsb = xs[it & 1];
      const size_t t0 = tok0 + (size_t)it * TB;
#pragma unroll
      for (int q = 0; q < QN; ++q) {
        const int o = q * CONS + tid;
        float2 e[WUNR];
#pragma unroll
        for (int j = 0; j < WUNR; ++j)
          e[j] = ell[(size_t)j * NN + o];            // coalesced dwordx2, L2-hit
        float a0 = 0.f, a1 = 0.f, a2 = 0.f, a3 = 0.f;
#pragma unroll
        for (int j = 0; j < WUNR; ++j) {
          const unsigned ix = __float_as_uint(e[j].x);
          const float w = e[j].y;
          const float4 xv = xsb[ix];                 // ds_read_b128: 4 tokens
          a0 = fmaf(xv.x, w, a0);
          a1 = fmaf(xv.y, w, a1);
          a2 = fmaf(xv.z, w, a2);
          a3 = fmaf(xv.w, w, a3);
        }
        for (int j = WUNR; j < cn[q]; ++j) {         // rare tail (degree > 8)
          const float2 et = ell[(size_t)j * NN + o];
          const unsigned ix = __float_as_uint(et.x);
          const float w = et.y;
          const float4 xv = xsb[ix];
          a0 = fmaf(xv.x, w, a0);
          a1 = fmaf(xv.y, w, a1);
          a2 = fmaf(xv.z, w, a2);
          a3 = fmaf(xv.w, w, a3);
        }
        float* op = out + t0 * NN + o;
        op[0]      = a0 + bs[q];
        op[NN]     = a1 + bs[q];
        op[2 * NN] = a2 + bs[q];
        op[3 * NN] = a3 + bs[q];
      }
    }
    asm volatile("s_waitcnt lgkmcnt(0)" ::: "memory");
    __builtin_amdgcn_s_barrier();
  }
}

extern "C" void kernel_launch(void* const* d_in, const int* in_sizes, int n_in,
                              void* d_out, int out_size, void* d_ws, size_t ws_size,
                              hipStream_t stream) {
  const float* x      = (const float*)d_in[0];
  const float* weight = (const float*)d_in[1];
  const float* bias   = (const float*)d_in[2];
  const float* mask   = (const float*)d_in[3];
  float* out = (float*)d_out;

  char* ws = (char*)d_ws;
  float2* ell = (float2*)ws;                                     // 1 MiB
  int*    cnt = (int*)(ws + (size_t)MAXD * NN * sizeof(float2)); // 16 KiB

  const int tokens = in_sizes[0] / NN;               // 16384
  const int nblk = tokens / (TB * ROUNDS);           // 256 -> 1 block/CU

  build_ell_kernel<<<NN, 64, 0, stream>>>(weight, mask, ell, cnt);
  ws_spmm_kernel<<<nblk, BLK, 0, stream>>>(x, bias, ell, cnt, out);
}

// Round 9
// 297.067 us; speedup vs baseline: 1.5187x; 1.1219x over previous
//
#include <hip/hip_runtime.h>

#define NN     4096
#define MAXD   32      // degree cap (WS k=4 max degree ~12)
#define WUNR   8       // fully-unrolled ELL width; rows with c>8 take tail loop
#define TB     4       // tokens per round
#define ROUNDS 16      // rounds per block -> 64 tokens/block
#define BLK    1024
#define QN     (NN / BLK)    // 4 output rows per thread
#define TILEW  (TB * NN)     // 16384 floats per tile

typedef __attribute__((address_space(3))) void       lds_void_t;
typedef const __attribute__((address_space(1))) void gbl_void_t;

// Phase 1: build padded ELL (column-major [j][o]) of W*M, deterministically.
// One wave per row; float4 mask reads + 4 ballots; prefix popcount keeps
// indices sorted ascending -> fixed fp32 summation order.
__global__ __launch_bounds__(64) void build_ell_kernel(
    const float* __restrict__ weight, const float* __restrict__ mask,
    float2* __restrict__ ell, int* __restrict__ cnt) {
  const int o = blockIdx.x;
  const int lane = threadIdx.x;
  if (lane < MAXD) {
    float2 z; z.x = __uint_as_float(0u); z.y = 0.0f;
    ell[(size_t)lane * NN + o] = z;
  }
  __syncthreads();
  const float* mrow = mask + (size_t)o * NN;
  const float* wrow = weight + (size_t)o * NN;
  const unsigned long long lt = (lane == 63) ? 0x7fffffffffffffffull
                                             : ((1ull << lane) - 1ull);
  int count = 0;
  for (int base = 0; base < NN; base += 256) {
    const int c0 = base + 4 * lane;
    const float4 mv = *(const float4*)(mrow + c0);
    const bool b0 = mv.x != 0.f, b1 = mv.y != 0.f, b2 = mv.z != 0.f, b3 = mv.w != 0.f;
    const unsigned long long a0 = __ballot(b0), a1 = __ballot(b1),
                             a2 = __ballot(b2), a3 = __ballot(b3);
    int pos = count + __popcll(a0 & lt) + __popcll(a1 & lt)
                    + __popcll(a2 & lt) + __popcll(a3 & lt);
    if (b0) { if (pos < MAXD) { float2 e; e.x = __uint_as_float(c0 + 0); e.y = wrow[c0 + 0]; ell[(size_t)pos * NN + o] = e; } ++pos; }
    if (b1) { if (pos < MAXD) { float2 e; e.x = __uint_as_float(c0 + 1); e.y = wrow[c0 + 1]; ell[(size_t)pos * NN + o] = e; } ++pos; }
    if (b2) { if (pos < MAXD) { float2 e; e.x = __uint_as_float(c0 + 2); e.y = wrow[c0 + 2]; ell[(size_t)pos * NN + o] = e; } ++pos; }
    if (b3) { if (pos < MAXD) { float2 e; e.x = __uint_as_float(c0 + 3); e.y = wrow[c0 + 3]; ell[(size_t)pos * NN + o] = e; } ++pos; }
    count += __popcll(a0) + __popcll(a1) + __popcll(a2) + __popcll(a3);
  }
  if (lane == 0) cnt[o] = (count < MAXD) ? count : MAXD;
}

// Phase 2: persistent double-buffered SpMM with transposing global_load_lds DMA.
//  - 256 blocks (1/CU), 1024 threads (16 waves), LDS = 2 x 64 KiB tiles.
//  - Staging: size=4 DMA, per-lane source x[(tok+ (l&3))*NN + c] -> LDS word
//    c*4 + t (the DMA performs the [t][c] -> [c][t] transpose; zero VGPR cost,
//    ~256 loads in flight per CU -> full HBM BW). Issued for tile it+1 BEFORE
//    computing tile it, so HBM latency hides under the gather phase.
//  - Consumer: ds_read_b128 = 4 tokens per ELL index (R3's proven gather).
//  - Round sync: vmcnt(0)+lgkmcnt(0)+s_barrier. The vmcnt(0) is cheap: DMAs
//    were issued a whole compute-phase ago; stores ack at L2.
__global__ __launch_bounds__(BLK) void ws_spmm_kernel(
    const float* __restrict__ x, const float* __restrict__ bias,
    const float2* __restrict__ ell, const int* __restrict__ cnt,
    float* __restrict__ out) {
  __shared__ float4 xs[2][NN];                       // 2 x 64 KiB
  const int tid  = threadIdx.x;
  const int wave = tid >> 6;                         // 0..15, wave-uniform
  const int lane = tid & 63;
  const size_t tok0 = (size_t)blockIdx.x * (TB * ROUNDS);

  float* xsf = (float*)xs;                           // flat word view

  // Per-lane DMA source decomposition: word = wave*1024 + k*64 + lane
  //   t = lane & 3, c = wave*256 + k*16 + (lane >> 2)
  const int srow  = lane & 3;
  const int scol0 = wave * 256 + (lane >> 2);

  // Hoist cnt/bias (8 regs).
  int   cn[QN];
  float bs[QN];
#pragma unroll
  for (int q = 0; q < QN; ++q) {
    cn[q] = cnt[q * BLK + tid];
    bs[q] = bias[q * BLK + tid];
  }

  // Prologue: DMA tile 0 into buf 0.
  {
    const float* src0 = x + (tok0 + srow) * NN + scol0;
    float* ldsb = &xsf[wave * 1024];
#pragma unroll
    for (int k = 0; k < 16; ++k)
      __builtin_amdgcn_global_load_lds((gbl_void_t*)(src0 + k * 16),
                                       (lds_void_t*)(ldsb + k * 64), 4, 0, 0);
  }
  asm volatile("s_waitcnt vmcnt(0)" ::: "memory");
  __builtin_amdgcn_s_barrier();

  for (int it = 0; it < ROUNDS; ++it) {
    const int cur = it & 1;

    // Issue next tile's DMA first (register-free, overlaps with compute).
    if (it + 1 < ROUNDS) {
      const float* srcn = x + (tok0 + (size_t)(it + 1) * TB + srow) * NN + scol0;
      float* ldsb = &xsf[(cur ^ 1) * TILEW + wave * 1024];
#pragma unroll
      for (int k = 0; k < 16; ++k)
        __builtin_amdgcn_global_load_lds((gbl_void_t*)(srcn + k * 16),
                                         (lds_void_t*)(ldsb + k * 64), 4, 0, 0);
    }

    // Compute current tile: QN output rows x 4 tokens per thread.
    const float4* __restrict__ xsb = xs[cur];
    const size_t t0 = tok0 + (size_t)it * TB;
#pragma unroll
    for (int q = 0; q < QN; ++q) {
      const int o = q * BLK + tid;
      float2 e[WUNR];
#pragma unroll
      for (int j = 0; j < WUNR; ++j)
        e[j] = ell[(size_t)j * NN + o];              // coalesced dwordx2, L2-hit
      float a0 = 0.f, a1 = 0.f, a2 = 0.f, a3 = 0.f;
#pragma unroll
      for (int j = 0; j < WUNR; ++j) {
        const unsigned ix = __float_as_uint(e[j].x);
        const float w = e[j].y;
        const float4 xv = xsb[ix];                   // ds_read_b128: 4 tokens
        a0 = fmaf(xv.x, w, a0);
        a1 = fmaf(xv.y, w, a1);
        a2 = fmaf(xv.z, w, a2);
        a3 = fmaf(xv.w, w, a3);
      }
      for (int j = WUNR; j < cn[q]; ++j) {           // rare tail (degree > 8)
        const float2 et = ell[(size_t)j * NN + o];
        const unsigned ix = __float_as_uint(et.x);
        const float w = et.y;
        const float4 xv = xsb[ix];
        a0 = fmaf(xv.x, w, a0);
        a1 = fmaf(xv.y, w, a1);
        a2 = fmaf(xv.z, w, a2);
        a3 = fmaf(xv.w, w, a3);
      }
      float* op = out + t0 * NN + o;
      op[0]      = a0 + bs[q];
      op[NN]     = a1 + bs[q];
      op[2 * NN] = a2 + bs[q];
      op[3 * NN] = a3 + bs[q];
    }

    // Round boundary: next tile's DMAs complete; own ds_reads drained.
    asm volatile("s_waitcnt vmcnt(0) lgkmcnt(0)" ::: "memory");
    __builtin_amdgcn_s_barrier();
  }
}

extern "C" void kernel_launch(void* const* d_in, const int* in_sizes, int n_in,
                              void* d_out, int out_size, void* d_ws, size_t ws_size,
                              hipStream_t stream) {
  const float* x      = (const float*)d_in[0];
  const float* weight = (const float*)d_in[1];
  const float* bias   = (const float*)d_in[2];
  const float* mask   = (const float*)d_in[3];
  float* out = (float*)d_out;

  char* ws = (char*)d_ws;
  float2* ell = (float2*)ws;                                     // 1 MiB
  int*    cnt = (int*)(ws + (size_t)MAXD * NN * sizeof(float2)); // 16 KiB

  const int tokens = in_sizes[0] / NN;               // 16384
  const int nblk = tokens / (TB * ROUNDS);           // 256 -> 1 block/CU

  build_ell_kernel<<<NN, 64, 0, stream>>>(weight, mask, ell, cnt);
  ws_spmm_kernel<<<nblk, BLK, 0, stream>>>(x, bias, ell, cnt, out);
}

// Round 10
// 203.882 us; speedup vs baseline: 2.2128x; 1.4571x over previous
//
#include <hip/hip_runtime.h>

#define NN     4096
#define MAXD   32      // degree cap (WS k=4 max degree ~12)
#define WUNR   8       // fully-unrolled ELL width; rows with c>8 take tail loop
#define TB     4       // tokens per round
#define ROUNDS 16      // rounds per block -> 64 tokens/block, grid = 256 = 1/CU
#define BLK    1024
#define QN     (NN / BLK)    // 4 column-chunks / output rows per thread

// Phase 1: build padded ELL (column-major [j][o]) of W*M, deterministically.
// One wave per row; float4 mask reads + 4 ballots; prefix popcount keeps
// indices sorted ascending -> fixed fp32 summation order.
__global__ __launch_bounds__(64) void build_ell_kernel(
    const float* __restrict__ weight, const float* __restrict__ mask,
    float2* __restrict__ ell, int* __restrict__ cnt) {
  const int o = blockIdx.x;
  const int lane = threadIdx.x;
  if (lane < MAXD) {
    float2 z; z.x = __uint_as_float(0u); z.y = 0.0f;
    ell[(size_t)lane * NN + o] = z;
  }
  __syncthreads();
  const float* mrow = mask + (size_t)o * NN;
  const float* wrow = weight + (size_t)o * NN;
  const unsigned long long lt = (lane == 63) ? 0x7fffffffffffffffull
                                             : ((1ull << lane) - 1ull);
  int count = 0;
  for (int base = 0; base < NN; base += 256) {
    const int c0 = base + 4 * lane;
    const float4 mv = *(const float4*)(mrow + c0);
    const bool b0 = mv.x != 0.f, b1 = mv.y != 0.f, b2 = mv.z != 0.f, b3 = mv.w != 0.f;
    const unsigned long long a0 = __ballot(b0), a1 = __ballot(b1),
                             a2 = __ballot(b2), a3 = __ballot(b3);
    int pos = count + __popcll(a0 & lt) + __popcll(a1 & lt)
                    + __popcll(a2 & lt) + __popcll(a3 & lt);
    if (b0) { if (pos < MAXD) { float2 e; e.x = __uint_as_float(c0 + 0); e.y = wrow[c0 + 0]; ell[(size_t)pos * NN + o] = e; } ++pos; }
    if (b1) { if (pos < MAXD) { float2 e; e.x = __uint_as_float(c0 + 1); e.y = wrow[c0 + 1]; ell[(size_t)pos * NN + o] = e; } ++pos; }
    if (b2) { if (pos < MAXD) { float2 e; e.x = __uint_as_float(c0 + 2); e.y = wrow[c0 + 2]; ell[(size_t)pos * NN + o] = e; } ++pos; }
    if (b3) { if (pos < MAXD) { float2 e; e.x = __uint_as_float(c0 + 3); e.y = wrow[c0 + 3]; ell[(size_t)pos * NN + o] = e; } ++pos; }
    count += __popcll(a0) + __popcll(a1) + __popcll(a2) + __popcll(a3);
  }
  if (lane == 0) cnt[o] = (count < MAXD) ? count : MAXD;
}

// Phase 2: persistent double-buffered SpMM with DRIP-FEED prefetch.
// 256 blocks (1/CU), 1024 threads, LDS = 2 x 64 KiB [col][4-token] tiles.
// Per q-chunk (4 per round, #pragma unroll 1 so loads stay interleaved):
//   issue 4 scalar loads of next tile's column c2 (lifetime = this q only),
//   gather-compute chunk q from xs[cur] (8 x ds_read_b128 = 4 tokens/index),
//   fire out-stores (stay in flight), ds_write_b128 the 4 loads -> xs[nxt]
//   (compiler emits a COUNTED vmcnt for just these 4 loads; they aged through
//   the gather). Loads are outstanding in every phase -> HBM duty ~100%.
// Round boundary: lgkmcnt(0) + raw s_barrier. NO vmcnt(0) in the loop.
__global__ __launch_bounds__(BLK) void ws_spmm_kernel(
    const float* __restrict__ x, const float* __restrict__ bias,
    const float2* __restrict__ ell, const int* __restrict__ cnt,
    float* __restrict__ out) {
  __shared__ float4 xs[2][NN];                       // 128 KiB -> 1 block/CU
  const int tid = threadIdx.x;
  const size_t tok0 = (size_t)blockIdx.x * (TB * ROUNDS);

  // Prologue: burst-stage tile 0 into buf 0.
  {
    const float* __restrict__ xb = x + tok0 * NN;
#pragma unroll
    for (int i = 0; i < QN; ++i) {
      const int c2 = tid + i * BLK;
      xs[0][c2] = make_float4(xb[c2], xb[NN + c2], xb[2 * NN + c2], xb[3 * NN + c2]);
    }
  }
  asm volatile("s_waitcnt lgkmcnt(0)" ::: "memory");
  __builtin_amdgcn_s_barrier();

  for (int it = 0; it < ROUNDS; ++it) {
    const int cur = it & 1;
    const float4* __restrict__ xsb = xs[cur];
    float4* __restrict__ xsn = xs[cur ^ 1];
    const size_t t0 = tok0 + (size_t)it * TB;
    const bool pf = (it + 1 < ROUNDS);
    const float* __restrict__ xnb = x + (t0 + TB) * NN;   // next tile base

#pragma unroll 1
    for (int q = 0; q < QN; ++q) {
      const int c2 = q * BLK + tid;                  // column chunk == output row o

      // Drip prefetch: 4 scalar coalesced loads, 4-register lifetime.
      float p0, p1, p2, p3;
      if (pf) {
        p0 = xnb[c2];
        p1 = xnb[NN + c2];
        p2 = xnb[2 * NN + c2];
        p3 = xnb[3 * NN + c2];
      }

      // Gather-compute output row o = c2 for the 4 current tokens.
      float2 e[WUNR];
#pragma unroll
      for (int j = 0; j < WUNR; ++j)
        e[j] = ell[(size_t)j * NN + c2];             // coalesced dwordx2, L2-hit
      const int c = cnt[c2];
      float a0 = 0.f, a1 = 0.f, a2 = 0.f, a3 = 0.f;
#pragma unroll
      for (int j = 0; j < WUNR; ++j) {
        const unsigned ix = __float_as_uint(e[j].x);
        const float w = e[j].y;
        const float4 xv = xsb[ix];                   // ds_read_b128: 4 tokens
        a0 = fmaf(xv.x, w, a0);
        a1 = fmaf(xv.y, w, a1);
        a2 = fmaf(xv.z, w, a2);
        a3 = fmaf(xv.w, w, a3);
      }
      for (int j = WUNR; j < c; ++j) {               // rare tail (degree > 8)
        const float2 et = ell[(size_t)j * NN + c2];
        const unsigned ix = __float_as_uint(et.x);
        const float w = et.y;
        const float4 xv = xsb[ix];
        a0 = fmaf(xv.x, w, a0);
        a1 = fmaf(xv.y, w, a1);
        a2 = fmaf(xv.z, w, a2);
        a3 = fmaf(xv.w, w, a3);
      }
      const float b = bias[c2];
      float* op = out + t0 * NN + c2;
      op[0]      = a0 + b;                           // fire-and-forget stores
      op[NN]     = a1 + b;
      op[2 * NN] = a2 + b;
      op[3 * NN] = a3 + b;

      // Transpose-write the drip chunk into the other buffer (counted vmcnt).
      if (pf) xsn[c2] = make_float4(p0, p1, p2, p3);
    }

    asm volatile("s_waitcnt lgkmcnt(0)" ::: "memory");
    __builtin_amdgcn_s_barrier();
  }
}

extern "C" void kernel_launch(void* const* d_in, const int* in_sizes, int n_in,
                              void* d_out, int out_size, void* d_ws, size_t ws_size,
                              hipStream_t stream) {
  const float* x      = (const float*)d_in[0];
  const float* weight = (const float*)d_in[1];
  const float* bias   = (const float*)d_in[2];
  const float* mask   = (const float*)d_in[3];
  float* out = (float*)d_out;

  char* ws = (char*)d_ws;
  float2* ell = (float2*)ws;                                     // 1 MiB
  int*    cnt = (int*)(ws + (size_t)MAXD * NN * sizeof(float2)); // 16 KiB

  const int tokens = in_sizes[0] / NN;               // 16384
  const int nblk = tokens / (TB * ROUNDS);           // 256 -> 1 block/CU

  build_ell_kernel<<<NN, 64, 0, stream>>>(weight, mask, ell, cnt);
  ws_spmm_kernel<<<nblk, BLK, 0, stream>>>(x, bias, ell, cnt, out);
}